// Round 7
// baseline (320.055 us; speedup 1.0000x reference)
//
#include <hip/hip_runtime.h>
#include <stdint.h>

#define B_ 4
#define S_ 2048
#define H_ 1024
#define NH_ 16
#define HD_ 64

typedef __bf16 bf16x8 __attribute__((ext_vector_type(8)));
typedef unsigned short u16x8 __attribute__((ext_vector_type(8)));
typedef float f32x4 __attribute__((ext_vector_type(4)));
typedef float f32x16 __attribute__((ext_vector_type(16)));

__device__ __forceinline__ unsigned short f2bf(float x) {
  union { float f; unsigned u; } c; c.f = x;
  unsigned r = (c.u + 0x7FFFu + ((c.u >> 16) & 1u)) >> 16;
  return (unsigned short)r;
}

__device__ __forceinline__ unsigned cvtpk(float lo, float hi) {
  unsigned r;
  asm("v_cvt_pk_bf16_f32 %0, %1, %2" : "=v"(r) : "v"(lo), "v"(hi));
  return r;
}

__device__ __forceinline__ void gload16(const unsigned short* g, unsigned short* lds) {
  __builtin_amdgcn_global_load_lds((const __attribute__((address_space(1))) void*)g,
                                   (__attribute__((address_space(3))) void*)lds, 16, 0, 0);
}

// ---------------- fp32 -> bf16 cast ----------------
__global__ __launch_bounds__(256) void cvt_kernel(const float* __restrict__ src,
                                                  unsigned short* __restrict__ dst, int n) {
  int i = (blockIdx.x * blockDim.x + threadIdx.x) * 4;
  if (i < n) {
    float4 v = *reinterpret_cast<const float4*>(src + i);
    ushort4 o;
    o.x = f2bf(v.x); o.y = f2bf(v.y); o.z = f2bf(v.z); o.w = f2bf(v.w);
    *reinterpret_cast<ushort4*>(dst + i) = o;
  }
}

// 4 weight matrices in one launch (blockIdx.y selects)
__global__ __launch_bounds__(256) void cvtw_kernel(const float* __restrict__ w0,
                                                   const float* __restrict__ w1,
                                                   const float* __restrict__ w2,
                                                   const float* __restrict__ w3,
                                                   unsigned short* __restrict__ o0,
                                                   unsigned short* __restrict__ o1,
                                                   unsigned short* __restrict__ o2,
                                                   unsigned short* __restrict__ o3, int n) {
  const int which = blockIdx.y;
  const float* src = (which == 0) ? w0 : (which == 1) ? w1 : (which == 2) ? w2 : w3;
  unsigned short* dst = (which == 0) ? o0 : (which == 1) ? o1 : (which == 2) ? o2 : o3;
  int i = (blockIdx.x * blockDim.x + threadIdx.x) * 4;
  if (i < n) {
    float4 v = *reinterpret_cast<const float4*>(src + i);
    ushort4 o;
    o.x = f2bf(v.x); o.y = f2bf(v.y); o.z = f2bf(v.z); o.w = f2bf(v.w);
    *reinterpret_cast<ushort4*>(dst + i) = o;
  }
}

// ---------------- bf16 GEMM, C[m,n] = sum_k A[m,k]*B[n,k] + bias[n] ----------------
template <bool BF16OUT>
__global__ __launch_bounds__(256) void gemm_bt(const unsigned short* __restrict__ A,
                                               const unsigned short* __restrict__ Bm,
                                               const float* __restrict__ bias,
                                               void* __restrict__ Cout,
                                               int M, int N, int K) {
  __shared__ unsigned short As[128 * 32];
  __shared__ unsigned short Bs[128 * 32];
  const int t = threadIdx.x;
  const int lane = t & 63;
  const int wv = t >> 6;
  const int wm = wv >> 1, wn = wv & 1;
  const int m0 = blockIdx.x * 128, n0 = blockIdx.y * 128;
  const int l15 = lane & 15, g8 = (lane >> 4) * 8;

  f32x4 acc[4][4];
#pragma unroll
  for (int i = 0; i < 4; ++i)
#pragma unroll
    for (int j = 0; j < 4; ++j) { f32x4 z = {0.f, 0.f, 0.f, 0.f}; acc[i][j] = z; }

  const int rowA = t >> 2;
  const int colA = (t & 3) * 8;
  const unsigned short* gA0 = A + (long)(m0 + rowA) * K + colA;
  const unsigned short* gA1 = A + (long)(m0 + 64 + rowA) * K + colA;
  const unsigned short* gB0 = Bm + (long)(n0 + rowA) * K + colA;
  const unsigned short* gB1 = Bm + (long)(n0 + 64 + rowA) * K + colA;
  unsigned short* ldsA0 = &As[wv * 512];
  unsigned short* ldsA1 = &As[2048 + wv * 512];
  unsigned short* ldsB0 = &Bs[wv * 512];
  unsigned short* ldsB1 = &Bs[2048 + wv * 512];

  for (int k0 = 0; k0 < K; k0 += 32) {
    __syncthreads();
    gload16(gA0 + k0, ldsA0);
    gload16(gA1 + k0, ldsA1);
    gload16(gB0 + k0, ldsB0);
    gload16(gB1 + k0, ldsB1);
    __syncthreads();

    bf16x8 af[4], bfr[4];
#pragma unroll
    for (int i = 0; i < 4; ++i)
      af[i] = *reinterpret_cast<const bf16x8*>(&As[(wm * 64 + i * 16 + l15) * 32 + g8]);
#pragma unroll
    for (int j = 0; j < 4; ++j)
      bfr[j] = *reinterpret_cast<const bf16x8*>(&Bs[(wn * 64 + j * 16 + l15) * 32 + g8]);
#pragma unroll
    for (int i = 0; i < 4; ++i)
#pragma unroll
      for (int j = 0; j < 4; ++j)
        acc[i][j] = __builtin_amdgcn_mfma_f32_16x16x32_bf16(af[i], bfr[j], acc[i][j], 0, 0, 0);
  }

  const int r0 = (lane >> 4) * 4;
#pragma unroll
  for (int i = 0; i < 4; ++i)
#pragma unroll
    for (int j = 0; j < 4; ++j) {
      int col = n0 + wn * 64 + j * 16 + l15;
      float bv = bias[col];
#pragma unroll
      for (int r = 0; r < 4; ++r) {
        int row = m0 + wm * 64 + i * 16 + r0 + r;
        float v = acc[i][j][r] + bv;
        if (BF16OUT)
          ((unsigned short*)Cout)[(long)row * N + col] = f2bf(v);
        else
          ((float*)Cout)[(long)row * N + col] = v;
      }
    }
}

// ---------------- flash attention, 32x32x16 MFMA, dbuf staging, 2-subtile pipeline ------
// grid (S/128, NH, B), 256 threads = 4 waves; wave owns 32 q-rows. KV tile 64.
// Pipeline per iter: LOADT(next) -> QK(sub0) -> QK(sub1) -> SM+PV(0) -> SM+PV(1)
// -> WRITET(next buf) -> barrier. QK(1) MFMAs overlap SM(0)'s VALU chain (T15).
// QK swapped: S = mfma(K, Q) -> col = q = lane&31, softmax lane-local, xor-32
// reduce, log2 domain (Q prescaled by 0.125*log2e). PV A-frag via cvt_pk +
// 2x v_permlane32_swap_b32 per kv-16 chunk. VtT XOR-swizzle: (d,kv) at
// d*72 + (kv&7) + 8*((kv>>3)^(d>>3)); read offsets hoisted out of the loop.
__global__ __launch_bounds__(256, 4) void attn_kernel(const unsigned short* __restrict__ Q,
                                                      const unsigned short* __restrict__ Kg,
                                                      const unsigned short* __restrict__ Vg,
                                                      const float* __restrict__ mask,
                                                      unsigned short* __restrict__ ctx) {
  __shared__ __align__(16) unsigned short Kt[2][64 * 72];
  __shared__ __align__(16) unsigned short VtT[2][64 * 72];
  __shared__ __align__(16) float biasL[2][64];
  __shared__ __align__(16) float alBuf[4][32];
  __shared__ int mflag[2];
  __shared__ int anyMsh;

  const int t = threadIdx.x, lane = t & 63;
  const int wv = t >> 6;
  const int h = blockIdx.y, b = blockIdx.z;
  const int q0w = blockIdx.x * 128 + wv * 32;
  const int l31 = lane & 31, h2 = lane >> 5;
  const long headoff = (long)h * HD_;
  const float L2E = 1.44269504088896f;
  const float SC = 0.125f * L2E;

  // ---- block-level mask scan: fast path when mask row is all ones ----
  if (t == 0) anyMsh = 0;
  __syncthreads();
  {
    bool nz = false;
    for (int i = t; i < S_; i += 256) nz |= (mask[(long)b * S_ + i] != 1.0f);
    if (__any(nz) && lane == 0) atomicOr(&anyMsh, 1);
  }

  // Q B-fragments, prescaled (overlaps mask scan latency)
  bf16x8 qf[4];
  {
    const unsigned short* Qrow = Q + ((long)(b * S_ + q0w + l31)) * H_ + headoff;
#pragma unroll
    for (int c = 0; c < 4; ++c) {
      bf16x8 raw = *reinterpret_cast<const bf16x8*>(Qrow + 16 * c + 8 * h2);
#pragma unroll
      for (int j = 0; j < 8; ++j) qf[c][j] = (__bf16)((float)raw[j] * SC);
    }
  }
  __syncthreads();
  const bool anyM = (anyMsh != 0);

  f32x16 o[2];
#pragma unroll
  for (int dt = 0; dt < 2; ++dt)
#pragma unroll
    for (int r = 0; r < 16; ++r) o[dt][r] = 0.f;
  float mrow = -1.0e30f, lsum = 0.f;

  const int rowd0 = l31, rowd1 = 32 + l31;
  const int grp0 = (rowd0 >> 3) & 7, grp1 = (rowd1 >> 3) & 7;

  // hoisted V read offsets (iteration-invariant)
  int voff0[4], voff1[4];
#pragma unroll
  for (int kc = 0; kc < 4; ++kc) {
    voff0[kc] = rowd0 * 72 + 8 * ((2 * kc + h2) ^ grp0);
    voff1[kc] = rowd1 * 72 + 8 * ((2 * kc + h2) ^ grp1);
  }

  // staging registers + addresses
  const int krow = t >> 3, kcg = (t & 7) * 8;   // K: rows krow, krow+32
  const int vrow = (t >> 3) * 2, dc = t & 7;    // V: rows vrow, vrow+1, d-block dc
  const long gbase = (long)(b * S_) * H_ + headoff;
  u16x8 kr0, kr1, vr0, vr1;

  auto LOADT = [&](int kv0) {
    kr0 = *reinterpret_cast<const u16x8*>(Kg + gbase + (long)(kv0 + krow) * H_ + kcg);
    kr1 = *reinterpret_cast<const u16x8*>(Kg + gbase + (long)(kv0 + krow + 32) * H_ + kcg);
    vr0 = *reinterpret_cast<const u16x8*>(Vg + gbase + (long)(kv0 + vrow) * H_ + dc * 8);
    vr1 = *reinterpret_cast<const u16x8*>(Vg + gbase + (long)(kv0 + vrow + 1) * H_ + dc * 8);
  };
  auto WRITET = [&](int buf, int kv0) {
    *reinterpret_cast<u16x8*>(&Kt[buf][krow * 72 + kcg]) = kr0;
    *reinterpret_cast<u16x8*>(&Kt[buf][(krow + 32) * 72 + kcg]) = kr1;
    const int pos = (vrow & 7) | (((vrow >> 3) ^ dc) << 3);
#pragma unroll
    for (int j = 0; j < 8; ++j) {
      ushort2 pr; pr.x = vr0[j]; pr.y = vr1[j];
      *reinterpret_cast<ushort2*>(&VtT[buf][(dc * 8 + j) * 72 + pos]) = pr;
    }
    if (anyM && t < 64) {  // slow path only: stage mask bias
      float mv = mask[(long)b * S_ + kv0 + t];
      biasL[buf][t] = (1.f - mv) * (-10000.f * L2E);
      unsigned long long bal = __ballot(mv != 1.0f);
      if (t == 0) mflag[buf] = (bal != 0ull);
    }
  };

  // softmax + PV for one 32-kv subtile (sequential state update)
  auto SMPV = [&](f32x16& sv, int kvt, int cur) {
    // max via v_max3-friendly triples
    float m0 = fmaxf(fmaxf(sv[0], sv[1]), sv[2]);
    float m1 = fmaxf(fmaxf(sv[3], sv[4]), sv[5]);
    float m2 = fmaxf(fmaxf(sv[6], sv[7]), sv[8]);
    float m3 = fmaxf(fmaxf(sv[9], sv[10]), sv[11]);
    float m4 = fmaxf(fmaxf(sv[12], sv[13]), sv[14]);
    float t0 = fmaxf(fmaxf(m0, m1), m2);
    float t1 = fmaxf(fmaxf(m3, m4), sv[15]);
    float tm = fmaxf(t0, t1);
    tm = fmaxf(tm, __shfl_xor(tm, 32));
    if (!__all(tm <= mrow + 8.0f)) {  // defer-max THR=8 (log2 domain)
      float mn = fmaxf(mrow, tm);
      float al = exp2f(mrow - mn);
      mrow = mn;
      lsum *= al;
      if (lane < 32) alBuf[wv][lane] = al;
      __builtin_amdgcn_wave_barrier();
#pragma unroll
      for (int m = 0; m < 4; ++m) {
        f32x4 av = *reinterpret_cast<const f32x4*>(&alBuf[wv][8 * m + 4 * h2]);
#pragma unroll
        for (int i = 0; i < 4; ++i) {
          o[0][4 * m + i] *= av[i];
          o[1][4 * m + i] *= av[i];
        }
      }
    }
#pragma unroll
    for (int r = 0; r < 16; ++r) sv[r] = exp2f(sv[r] - mrow);
    {
      float s0 = sv[0] + sv[1], s1 = sv[2] + sv[3], s2 = sv[4] + sv[5], s3 = sv[6] + sv[7];
      float s4 = sv[8] + sv[9], s5 = sv[10] + sv[11], s6 = sv[12] + sv[13], s7 = sv[14] + sv[15];
      float u0 = s0 + s1, u1 = s2 + s3, u2 = s4 + s5, u3 = s6 + s7;
      float ts = (u0 + u1) + (u2 + u3);
      ts += __shfl_xor(ts, 32);
      lsum += ts;
    }
    // PV per kv-16 chunk: cvt_pk -> permlane swap -> 2 MFMA
#pragma unroll
    for (int c2 = 0; c2 < 2; ++c2) {
      const int kc = 2 * kvt + c2;
      unsigned p0 = cvtpk(sv[8 * c2 + 0], sv[8 * c2 + 1]);
      unsigned p1 = cvtpk(sv[8 * c2 + 2], sv[8 * c2 + 3]);
      unsigned p2 = cvtpk(sv[8 * c2 + 4], sv[8 * c2 + 5]);
      unsigned p3 = cvtpk(sv[8 * c2 + 6], sv[8 * c2 + 7]);
      asm("v_permlane32_swap_b32 %0, %1" : "+v"(p0), "+v"(p2));
      asm("v_permlane32_swap_b32 %0, %1" : "+v"(p1), "+v"(p3));
      union { unsigned w[4]; bf16x8 v; } fa;
      fa.w[0] = p0; fa.w[1] = p1; fa.w[2] = p2; fa.w[3] = p3;

      bf16x8 vb0 = *reinterpret_cast<const bf16x8*>(&VtT[cur][voff0[kc]]);
      bf16x8 vb1 = *reinterpret_cast<const bf16x8*>(&VtT[cur][voff1[kc]]);
      __builtin_amdgcn_s_setprio(1);
      o[0] = __builtin_amdgcn_mfma_f32_32x32x16_bf16(fa.v, vb0, o[0], 0, 0, 0);
      o[1] = __builtin_amdgcn_mfma_f32_32x32x16_bf16(fa.v, vb1, o[1], 0, 0, 0);
      __builtin_amdgcn_s_setprio(0);
    }
  };

  const int NT = S_ / 64;
  LOADT(0);
  WRITET(0, 0);
  __syncthreads();

  for (int it = 0; it < NT; ++it) {
    const int cur = it & 1;
    const bool more = (it + 1 < NT);
    if (more) LOADT((it + 1) * 64);

    const unsigned short* KtA = &Kt[cur][l31 * 72 + 8 * h2];

    // QK both subtiles first: sub1's MFMAs overlap sub0's softmax VALU chain
    f32x16 sv0, sv1;
#pragma unroll
    for (int r = 0; r < 16; ++r) { sv0[r] = 0.f; sv1[r] = 0.f; }
    __builtin_amdgcn_s_setprio(1);
#pragma unroll
    for (int c = 0; c < 4; ++c) {
      bf16x8 af = *reinterpret_cast<const bf16x8*>(KtA + 16 * c);
      sv0 = __builtin_amdgcn_mfma_f32_32x32x16_bf16(af, qf[c], sv0, 0, 0, 0);
    }
#pragma unroll
    for (int c = 0; c < 4; ++c) {
      bf16x8 af = *reinterpret_cast<const bf16x8*>(KtA + 32 * 72 + 16 * c);
      sv1 = __builtin_amdgcn_mfma_f32_32x32x16_bf16(af, qf[c], sv1, 0, 0, 0);
    }
    __builtin_amdgcn_s_setprio(0);

    if (anyM && mflag[cur]) {  // slow path: additive mask bias
#pragma unroll
      for (int m = 0; m < 4; ++m) {
        f32x4 b0 = *reinterpret_cast<const f32x4*>(&biasL[cur][8 * m + 4 * h2]);
        f32x4 b1 = *reinterpret_cast<const f32x4*>(&biasL[cur][32 + 8 * m + 4 * h2]);
#pragma unroll
        for (int i = 0; i < 4; ++i) { sv0[4 * m + i] += b0[i]; sv1[4 * m + i] += b1[i]; }
      }
    }

    SMPV(sv0, 0, cur);
    SMPV(sv1, 1, cur);

    if (more) {
      WRITET(cur ^ 1, (it + 1) * 64);
      __syncthreads();
    }
  }

  // ---- epilogue ----
  if (lane < 32) alBuf[wv][lane] = 1.0f / lsum;
  __builtin_amdgcn_wave_barrier();
  unsigned short* ctxbase = ctx + ((long)(b * S_ + q0w + 4 * h2)) * H_ + headoff + l31;
#pragma unroll
  for (int m = 0; m < 4; ++m) {
    f32x4 iv = *reinterpret_cast<const f32x4*>(&alBuf[wv][8 * m + 4 * h2]);
#pragma unroll
    for (int i = 0; i < 4; ++i) {
#pragma unroll
      for (int dt = 0; dt < 2; ++dt)
        ctxbase[(long)(8 * m + i) * H_ + dt * 32] = f2bf(o[dt][4 * m + i] * iv[i]);
    }
  }
}

// ---------------- residual + LayerNorm ----------------
__global__ __launch_bounds__(256) void ln_kernel(const float* __restrict__ proj,
                                                 const float* __restrict__ hs,
                                                 const float* __restrict__ gam,
                                                 const float* __restrict__ bet,
                                                 float* __restrict__ out) {
  const int row = blockIdx.x;
  const int t = threadIdx.x;
  const long base = (long)row * H_ + t * 4;
  float4 a = *reinterpret_cast<const float4*>(proj + base);
  float4 hv = *reinterpret_cast<const float4*>(hs + base);
  float x0 = a.x + hv.x, x1 = a.y + hv.y, x2 = a.z + hv.z, x3 = a.w + hv.w;
  float s1 = x0 + x1 + x2 + x3;
  float s2 = x0 * x0 + x1 * x1 + x2 * x2 + x3 * x3;
#pragma unroll
  for (int off = 1; off < 64; off <<= 1) {
    s1 += __shfl_xor(s1, off);
    s2 += __shfl_xor(s2, off);
  }
  __shared__ float a1[4], a2[4];
  if ((t & 63) == 0) { a1[t >> 6] = s1; a2[t >> 6] = s2; }
  __syncthreads();
  float ts1 = a1[0] + a1[1] + a1[2] + a1[3];
  float ts2 = a2[0] + a2[1] + a2[2] + a2[3];
  float mu = ts1 * (1.0f / H_);
  float var = ts2 * (1.0f / H_) - mu * mu;
  float inv = rsqrtf(var + 1e-12f);
  float4 gv = *reinterpret_cast<const float4*>(gam + t * 4);
  float4 bb = *reinterpret_cast<const float4*>(bet + t * 4);
  float4 ov;
  ov.x = (x0 - mu) * inv * gv.x + bb.x;
  ov.y = (x1 - mu) * inv * gv.y + bb.y;
  ov.z = (x2 - mu) * inv * gv.z + bb.z;
  ov.w = (x3 - mu) * inv * gv.w + bb.w;
  *reinterpret_cast<float4*>(out + base) = ov;
}

extern "C" void kernel_launch(void* const* d_in, const int* in_sizes, int n_in,
                              void* d_out, int out_size, void* d_ws, size_t ws_size,
                              hipStream_t stream) {
  const float* hs   = (const float*)d_in[0];
  const float* mask = (const float*)d_in[1];
  const float* Wq   = (const float*)d_in[2];
  const float* bq   = (const float*)d_in[3];
  const float* Wk   = (const float*)d_in[4];
  const float* bk   = (const float*)d_in[5];
  const float* Wv   = (const float*)d_in[6];
  const float* bv   = (const float*)d_in[7];
  const float* Wd   = (const float*)d_in[8];
  const float* bd   = (const float*)d_in[9];
  const float* lng  = (const float*)d_in[10];
  const float* lnb  = (const float*)d_in[11];
  float* out = (float*)d_out;

  char* ws = (char*)d_ws;
  const size_t SZ_X = (size_t)B_ * S_ * H_ * 2;
  const size_t SZ_W = (size_t)H_ * H_ * 2;
  unsigned short* Xb  = (unsigned short*)(ws);
  unsigned short* Wqb = (unsigned short*)(ws + SZ_X);
  unsigned short* Wkb = (unsigned short*)(ws + SZ_X + SZ_W);
  unsigned short* Wvb = (unsigned short*)(ws + SZ_X + 2 * SZ_W);
  unsigned short* Wdb = (unsigned short*)(ws + SZ_X + 3 * SZ_W);
  unsigned short* Qb  = (unsigned short*)(ws + SZ_X + 4 * SZ_W);
  unsigned short* Kb  = (unsigned short*)(ws + 2 * SZ_X + 4 * SZ_W);
  unsigned short* Vb  = (unsigned short*)(ws + 3 * SZ_X + 4 * SZ_W);
  unsigned short* Cxb = (unsigned short*)(ws + 4 * SZ_X + 4 * SZ_W);
  float* Proj         = (float*)(ws + 5 * SZ_X + 4 * SZ_W);

  const int NX = B_ * S_ * H_;
  const int NW = H_ * H_;

  cvt_kernel<<<NX / 1024, 256, 0, stream>>>(hs, Xb, NX);
  dim3 gw(NW / 1024, 4);
  cvtw_kernel<<<gw, 256, 0, stream>>>(Wq, Wk, Wv, Wd, Wqb, Wkb, Wvb, Wdb, NW);

  dim3 gg(B_ * S_ / 128, H_ / 128);
  gemm_bt<true><<<gg, 256, 0, stream>>>(Xb, Wqb, bq, Qb, B_ * S_, H_, H_);
  gemm_bt<true><<<gg, 256, 0, stream>>>(Xb, Wkb, bk, Kb, B_ * S_, H_, H_);
  gemm_bt<true><<<gg, 256, 0, stream>>>(Xb, Wvb, bv, Vb, B_ * S_, H_, H_);

  dim3 ga(S_ / 128, NH_, B_);  // (16, 16, 4)
  attn_kernel<<<ga, 256, 0, stream>>>(Qb, Kb, Vb, mask, Cxb);

  gemm_bt<false><<<gg, 256, 0, stream>>>(Cxb, Wdb, bd, Proj, B_ * S_, H_, H_);

  ln_kernel<<<B_ * S_, 256, 0, stream>>>(Proj, hs, lng, lnb, out);
}

// Round 8
// 292.819 us; speedup vs baseline: 1.0930x; 1.0930x over previous
//
#include <hip/hip_runtime.h>
#include <stdint.h>

#define B_ 4
#define S_ 2048
#define H_ 1024
#define NH_ 16
#define HD_ 64

typedef __bf16 bf16x8 __attribute__((ext_vector_type(8)));
typedef unsigned short u16x8 __attribute__((ext_vector_type(8)));
typedef float f32x4 __attribute__((ext_vector_type(4)));
typedef float f32x16 __attribute__((ext_vector_type(16)));

__device__ __forceinline__ unsigned short f2bf(float x) {
  union { float f; unsigned u; } c; c.f = x;
  unsigned r = (c.u + 0x7FFFu + ((c.u >> 16) & 1u)) >> 16;
  return (unsigned short)r;
}

__device__ __forceinline__ unsigned cvtpk(float lo, float hi) {
  unsigned r;
  asm("v_cvt_pk_bf16_f32 %0, %1, %2" : "=v"(r) : "v"(lo), "v"(hi));
  return r;
}

__device__ __forceinline__ void gload16(const unsigned short* g, unsigned short* lds) {
  __builtin_amdgcn_global_load_lds((const __attribute__((address_space(1))) void*)g,
                                   (__attribute__((address_space(3))) void*)lds, 16, 0, 0);
}

// ---------------- fp32 -> bf16 cast ----------------
__global__ __launch_bounds__(256) void cvt_kernel(const float* __restrict__ src,
                                                  unsigned short* __restrict__ dst, int n) {
  int i = (blockIdx.x * blockDim.x + threadIdx.x) * 4;
  if (i < n) {
    float4 v = *reinterpret_cast<const float4*>(src + i);
    ushort4 o;
    o.x = f2bf(v.x); o.y = f2bf(v.y); o.z = f2bf(v.z); o.w = f2bf(v.w);
    *reinterpret_cast<ushort4*>(dst + i) = o;
  }
}

// 4 weight matrices in one launch (blockIdx.y selects)
__global__ __launch_bounds__(256) void cvtw_kernel(const float* __restrict__ w0,
                                                   const float* __restrict__ w1,
                                                   const float* __restrict__ w2,
                                                   const float* __restrict__ w3,
                                                   unsigned short* __restrict__ o0,
                                                   unsigned short* __restrict__ o1,
                                                   unsigned short* __restrict__ o2,
                                                   unsigned short* __restrict__ o3, int n) {
  const int which = blockIdx.y;
  const float* src = (which == 0) ? w0 : (which == 1) ? w1 : (which == 2) ? w2 : w3;
  unsigned short* dst = (which == 0) ? o0 : (which == 1) ? o1 : (which == 2) ? o2 : o3;
  int i = (blockIdx.x * blockDim.x + threadIdx.x) * 4;
  if (i < n) {
    float4 v = *reinterpret_cast<const float4*>(src + i);
    ushort4 o;
    o.x = f2bf(v.x); o.y = f2bf(v.y); o.z = f2bf(v.z); o.w = f2bf(v.w);
    *reinterpret_cast<ushort4*>(dst + i) = o;
  }
}

// ---------------- bf16 GEMM, C[m,n] = sum_k A[m,k]*B[n,k] + bias[n] ----------------
template <bool BF16OUT>
__global__ __launch_bounds__(256) void gemm_bt(const unsigned short* __restrict__ A,
                                               const unsigned short* __restrict__ Bm,
                                               const float* __restrict__ bias,
                                               void* __restrict__ Cout,
                                               int M, int N, int K) {
  __shared__ unsigned short As[128 * 32];
  __shared__ unsigned short Bs[128 * 32];
  const int t = threadIdx.x;
  const int lane = t & 63;
  const int wv = t >> 6;
  const int wm = wv >> 1, wn = wv & 1;
  const int m0 = blockIdx.x * 128, n0 = blockIdx.y * 128;
  const int l15 = lane & 15, g8 = (lane >> 4) * 8;

  f32x4 acc[4][4];
#pragma unroll
  for (int i = 0; i < 4; ++i)
#pragma unroll
    for (int j = 0; j < 4; ++j) { f32x4 z = {0.f, 0.f, 0.f, 0.f}; acc[i][j] = z; }

  const int rowA = t >> 2;
  const int colA = (t & 3) * 8;
  const unsigned short* gA0 = A + (long)(m0 + rowA) * K + colA;
  const unsigned short* gA1 = A + (long)(m0 + 64 + rowA) * K + colA;
  const unsigned short* gB0 = Bm + (long)(n0 + rowA) * K + colA;
  const unsigned short* gB1 = Bm + (long)(n0 + 64 + rowA) * K + colA;
  unsigned short* ldsA0 = &As[wv * 512];
  unsigned short* ldsA1 = &As[2048 + wv * 512];
  unsigned short* ldsB0 = &Bs[wv * 512];
  unsigned short* ldsB1 = &Bs[2048 + wv * 512];

  for (int k0 = 0; k0 < K; k0 += 32) {
    __syncthreads();
    gload16(gA0 + k0, ldsA0);
    gload16(gA1 + k0, ldsA1);
    gload16(gB0 + k0, ldsB0);
    gload16(gB1 + k0, ldsB1);
    __syncthreads();

    bf16x8 af[4], bfr[4];
#pragma unroll
    for (int i = 0; i < 4; ++i)
      af[i] = *reinterpret_cast<const bf16x8*>(&As[(wm * 64 + i * 16 + l15) * 32 + g8]);
#pragma unroll
    for (int j = 0; j < 4; ++j)
      bfr[j] = *reinterpret_cast<const bf16x8*>(&Bs[(wn * 64 + j * 16 + l15) * 32 + g8]);
#pragma unroll
    for (int i = 0; i < 4; ++i)
#pragma unroll
      for (int j = 0; j < 4; ++j)
        acc[i][j] = __builtin_amdgcn_mfma_f32_16x16x32_bf16(af[i], bfr[j], acc[i][j], 0, 0, 0);
  }

  const int r0 = (lane >> 4) * 4;
#pragma unroll
  for (int i = 0; i < 4; ++i)
#pragma unroll
    for (int j = 0; j < 4; ++j) {
      int col = n0 + wn * 64 + j * 16 + l15;
      float bv = bias[col];
#pragma unroll
      for (int r = 0; r < 4; ++r) {
        int row = m0 + wm * 64 + i * 16 + r0 + r;
        float v = acc[i][j][r] + bv;
        if (BF16OUT)
          ((unsigned short*)Cout)[(long)row * N + col] = f2bf(v);
        else
          ((float*)Cout)[(long)row * N + col] = v;
      }
    }
}

// ---------------- flash attention, 32x32x16 MFMA, dbuf, DMA K-staging, XCD swizzle ------
// Flat grid 1024; decode: bh = (id>>7)*8 + (id&7), qb = (id>>3)&15 -> all 16
// q-blocks of one (b,h) land on one XCD (dispatch RR by id&7) so the 512 KB
// K/V slice is L2-resident. 256 threads = 4 waves; wave owns 32 q-rows.
// KV tile 64, two subtiles of 32, double-buffered.
// K staged by global_load_lds into LINEAR Kt[64][64] with PRE-SWIZZLED global
// source: dest slot (lane&7) of row (lane>>3) receives col-group
// (lane&7)^(lane>>3); reads use koff[c] = 8*((2c+h2)^(l31&7)) -> b128 reads hit
// the 8-lane/bank floor. V reg-staged + transposed + XOR swizzle as before.
// QK swapped: S = mfma(K, Q) -> q = lane&31 col; softmax lane-local (xor-32),
// log2 domain (Q prescaled 0.125*log2e), defer-max THR=8. PV A-frag via
// cvt_pk + 2x v_permlane32_swap_b32 per kv-16 chunk.
__global__ __launch_bounds__(256) void attn_kernel(const unsigned short* __restrict__ Q,
                                                   const unsigned short* __restrict__ Kg,
                                                   const unsigned short* __restrict__ Vg,
                                                   const float* __restrict__ mask,
                                                   unsigned short* __restrict__ ctx) {
  __shared__ __align__(16) unsigned short Kt[2][64 * 64];   // linear, DMA-written
  __shared__ __align__(16) unsigned short VtT[2][64 * 72];  // [d][kv swizzled], padded
  __shared__ __align__(16) float biasL[2][64];
  __shared__ __align__(16) float alBuf[4][32];
  __shared__ int mflag[2];
  __shared__ int anyMsh;

  const int t = threadIdx.x, lane = t & 63;
  const int wv = t >> 6;
  const int id = blockIdx.x;
  const int bh = ((id >> 7) << 3) | (id & 7);
  const int qb = (id >> 3) & 15;
  const int h = bh & 15, b = bh >> 4;
  const int q0w = qb * 128 + wv * 32;
  const int l31 = lane & 31, h2 = lane >> 5;
  const long headoff = (long)h * HD_;
  const float L2E = 1.44269504088896f;
  const float SC = 0.125f * L2E;

  // ---- block-level mask scan: fast path when mask row is all ones ----
  if (t == 0) anyMsh = 0;
  __syncthreads();
  {
    bool nz = false;
    for (int i = t; i < S_; i += 256) nz |= (mask[(long)b * S_ + i] != 1.0f);
    if (__any(nz) && lane == 0) atomicOr(&anyMsh, 1);
  }

  // Q B-fragments, prescaled (overlaps mask scan latency)
  bf16x8 qf[4];
  {
    const unsigned short* Qrow = Q + ((long)(b * S_ + q0w + l31)) * H_ + headoff;
#pragma unroll
    for (int c = 0; c < 4; ++c) {
      bf16x8 raw = *reinterpret_cast<const bf16x8*>(Qrow + 16 * c + 8 * h2);
#pragma unroll
      for (int j = 0; j < 8; ++j) qf[c][j] = (__bf16)((float)raw[j] * SC);
    }
  }
  __syncthreads();
  const bool anyM = (anyMsh != 0);

  f32x16 o[2];
#pragma unroll
  for (int dt = 0; dt < 2; ++dt)
#pragma unroll
    for (int r = 0; r < 16; ++r) o[dt][r] = 0.f;
  float mrow = -1.0e30f, lsum = 0.f;

  // K read offsets (swizzled, loop-invariant)
  int koff[4];
#pragma unroll
  for (int c = 0; c < 4; ++c) koff[c] = 8 * ((2 * c + h2) ^ (l31 & 7));

  // V read offsets (swizzled, loop-invariant)
  const int rowd0 = l31, rowd1 = 32 + l31;
  const int grp0 = (rowd0 >> 3) & 7, grp1 = (rowd1 >> 3) & 7;
  int voff0[4], voff1[4];
#pragma unroll
  for (int kc = 0; kc < 4; ++kc) {
    voff0[kc] = rowd0 * 72 + 8 * ((2 * kc + h2) ^ grp0);
    voff1[kc] = rowd1 * 72 + 8 * ((2 * kc + h2) ^ grp1);
  }

  const long gbase = (long)(b * S_) * H_ + headoff;

  // K DMA source (pre-swizzled): wave wv, chunk i covers rows 16wv+8i..+7;
  // lane supplies row (lane>>3), col-group (lane&7)^(lane>>3).
  const unsigned short* kg0 =
      Kg + gbase + (long)(16 * wv + (lane >> 3)) * H_ + 8 * ((lane & 7) ^ (lane >> 3));
  const unsigned short* kg1 = kg0 + 8 * H_;

  // V staging (regs): rows vrow, vrow+1, d-block dc
  const int vrow = (t >> 3) * 2, dc = t & 7;
  u16x8 vr0, vr1;

  auto LOADK = [&](int buf, int kv0) {
    gload16(kg0 + (long)kv0 * H_, &Kt[buf][(16 * wv) * 64]);
    gload16(kg1 + (long)kv0 * H_, &Kt[buf][(16 * wv + 8) * 64]);
  };
  auto LOADV = [&](int kv0) {
    vr0 = *reinterpret_cast<const u16x8*>(Vg + gbase + (long)(kv0 + vrow) * H_ + dc * 8);
    vr1 = *reinterpret_cast<const u16x8*>(Vg + gbase + (long)(kv0 + vrow + 1) * H_ + dc * 8);
  };
  auto WRITEV = [&](int buf, int kv0) {
    const int pos = (vrow & 7) | (((vrow >> 3) ^ dc) << 3);
#pragma unroll
    for (int j = 0; j < 8; ++j) {
      ushort2 pr; pr.x = vr0[j]; pr.y = vr1[j];
      *reinterpret_cast<ushort2*>(&VtT[buf][(dc * 8 + j) * 72 + pos]) = pr;
    }
    if (anyM && t < 64) {
      float mv = mask[(long)b * S_ + kv0 + t];
      biasL[buf][t] = (1.f - mv) * (-10000.f * L2E);
      unsigned long long bal = __ballot(mv != 1.0f);
      if (t == 0) mflag[buf] = (bal != 0ull);
    }
  };

  // softmax + PV for one 32-kv subtile
  auto SMPV = [&](f32x16& sv, int kvt, int cur) {
    float m0 = fmaxf(fmaxf(sv[0], sv[1]), sv[2]);
    float m1 = fmaxf(fmaxf(sv[3], sv[4]), sv[5]);
    float m2 = fmaxf(fmaxf(sv[6], sv[7]), sv[8]);
    float m3 = fmaxf(fmaxf(sv[9], sv[10]), sv[11]);
    float m4 = fmaxf(fmaxf(sv[12], sv[13]), sv[14]);
    float t0 = fmaxf(fmaxf(m0, m1), m2);
    float t1 = fmaxf(fmaxf(m3, m4), sv[15]);
    float tm = fmaxf(t0, t1);
    tm = fmaxf(tm, __shfl_xor(tm, 32));
    if (!__all(tm <= mrow + 8.0f)) {  // defer-max THR=8 (log2 domain)
      float mn = fmaxf(mrow, tm);
      float al = exp2f(mrow - mn);
      mrow = mn;
      lsum *= al;
      if (lane < 32) alBuf[wv][lane] = al;
      __builtin_amdgcn_wave_barrier();
#pragma unroll
      for (int m = 0; m < 4; ++m) {
        f32x4 av = *reinterpret_cast<const f32x4*>(&alBuf[wv][8 * m + 4 * h2]);
#pragma unroll
        for (int i = 0; i < 4; ++i) {
          o[0][4 * m + i] *= av[i];
          o[1][4 * m + i] *= av[i];
        }
      }
    }
#pragma unroll
    for (int r = 0; r < 16; ++r) sv[r] = exp2f(sv[r] - mrow);
    {
      float s0 = sv[0] + sv[1], s1 = sv[2] + sv[3], s2 = sv[4] + sv[5], s3 = sv[6] + sv[7];
      float s4 = sv[8] + sv[9], s5 = sv[10] + sv[11], s6 = sv[12] + sv[13], s7 = sv[14] + sv[15];
      float u0 = s0 + s1, u1 = s2 + s3, u2 = s4 + s5, u3 = s6 + s7;
      float ts = (u0 + u1) + (u2 + u3);
      ts += __shfl_xor(ts, 32);
      lsum += ts;
    }
#pragma unroll
    for (int c2 = 0; c2 < 2; ++c2) {
      const int kc = 2 * kvt + c2;
      unsigned p0 = cvtpk(sv[8 * c2 + 0], sv[8 * c2 + 1]);
      unsigned p1 = cvtpk(sv[8 * c2 + 2], sv[8 * c2 + 3]);
      unsigned p2 = cvtpk(sv[8 * c2 + 4], sv[8 * c2 + 5]);
      unsigned p3 = cvtpk(sv[8 * c2 + 6], sv[8 * c2 + 7]);
      asm("v_permlane32_swap_b32 %0, %1" : "+v"(p0), "+v"(p2));
      asm("v_permlane32_swap_b32 %0, %1" : "+v"(p1), "+v"(p3));
      union { unsigned w[4]; bf16x8 v; } fa;
      fa.w[0] = p0; fa.w[1] = p1; fa.w[2] = p2; fa.w[3] = p3;

      bf16x8 vb0 = *reinterpret_cast<const bf16x8*>(&VtT[cur][voff0[kc]]);
      bf16x8 vb1 = *reinterpret_cast<const bf16x8*>(&VtT[cur][voff1[kc]]);
      __builtin_amdgcn_s_setprio(1);
      o[0] = __builtin_amdgcn_mfma_f32_32x32x16_bf16(fa.v, vb0, o[0], 0, 0, 0);
      o[1] = __builtin_amdgcn_mfma_f32_32x32x16_bf16(fa.v, vb1, o[1], 0, 0, 0);
      __builtin_amdgcn_s_setprio(0);
    }
  };

  const int NT = S_ / 64;
  LOADK(0, 0);
  LOADV(0);
  WRITEV(0, 0);
  __syncthreads();  // drains DMA (vmcnt) + V writes

  for (int it = 0; it < NT; ++it) {
    const int cur = it & 1;
    const bool more = (it + 1 < NT);
    if (more) {
      LOADK(cur ^ 1, (it + 1) * 64);  // DMA direct to other buffer
      LOADV((it + 1) * 64);           // regs; latency hides under compute
    }

#pragma unroll
    for (int kvt = 0; kvt < 2; ++kvt) {
      f32x16 sv;
#pragma unroll
      for (int r = 0; r < 16; ++r) sv[r] = 0.f;
      const int rb = (kvt * 32 + l31) * 64;
      __builtin_amdgcn_s_setprio(1);
#pragma unroll
      for (int c = 0; c < 4; ++c) {
        bf16x8 af = *reinterpret_cast<const bf16x8*>(&Kt[cur][rb + koff[c]]);
        sv = __builtin_amdgcn_mfma_f32_32x32x16_bf16(af, qf[c], sv, 0, 0, 0);
      }
      __builtin_amdgcn_s_setprio(0);
      if (anyM && mflag[cur]) {
#pragma unroll
        for (int m = 0; m < 4; ++m) {
          f32x4 bb = *reinterpret_cast<const f32x4*>(&biasL[cur][kvt * 32 + 8 * m + 4 * h2]);
#pragma unroll
          for (int i = 0; i < 4; ++i) sv[4 * m + i] += bb[i];
        }
      }
      SMPV(sv, kvt, cur);
    }

    if (more) {
      WRITEV(cur ^ 1, (it + 1) * 64);
      __syncthreads();  // V visible + K DMA drained for next iter
    }
  }

  // ---- epilogue ----
  if (lane < 32) alBuf[wv][lane] = 1.0f / lsum;
  __builtin_amdgcn_wave_barrier();
  unsigned short* ctxbase = ctx + ((long)(b * S_ + q0w + 4 * h2)) * H_ + headoff + l31;
#pragma unroll
  for (int m = 0; m < 4; ++m) {
    f32x4 iv = *reinterpret_cast<const f32x4*>(&alBuf[wv][8 * m + 4 * h2]);
#pragma unroll
    for (int i = 0; i < 4; ++i) {
#pragma unroll
      for (int dt = 0; dt < 2; ++dt)
        ctxbase[(long)(8 * m + i) * H_ + dt * 32] = f2bf(o[dt][4 * m + i] * iv[i]);
    }
  }
}

// ---------------- residual + LayerNorm ----------------
__global__ __launch_bounds__(256) void ln_kernel(const float* __restrict__ proj,
                                                 const float* __restrict__ hs,
                                                 const float* __restrict__ gam,
                                                 const float* __restrict__ bet,
                                                 float* __restrict__ out) {
  const int row = blockIdx.x;
  const int t = threadIdx.x;
  const long base = (long)row * H_ + t * 4;
  float4 a = *reinterpret_cast<const float4*>(proj + base);
  float4 hv = *reinterpret_cast<const float4*>(hs + base);
  float x0 = a.x + hv.x, x1 = a.y + hv.y, x2 = a.z + hv.z, x3 = a.w + hv.w;
  float s1 = x0 + x1 + x2 + x3;
  float s2 = x0 * x0 + x1 * x1 + x2 * x2 + x3 * x3;
#pragma unroll
  for (int off = 1; off < 64; off <<= 1) {
    s1 += __shfl_xor(s1, off);
    s2 += __shfl_xor(s2, off);
  }
  __shared__ float a1[4], a2[4];
  if ((t & 63) == 0) { a1[t >> 6] = s1; a2[t >> 6] = s2; }
  __syncthreads();
  float ts1 = a1[0] + a1[1] + a1[2] + a1[3];
  float ts2 = a2[0] + a2[1] + a2[2] + a2[3];
  float mu = ts1 * (1.0f / H_);
  float var = ts2 * (1.0f / H_) - mu * mu;
  float inv = rsqrtf(var + 1e-12f);
  float4 gv = *reinterpret_cast<const float4*>(gam + t * 4);
  float4 bb = *reinterpret_cast<const float4*>(bet + t * 4);
  float4 ov;
  ov.x = (x0 - mu) * inv * gv.x + bb.x;
  ov.y = (x1 - mu) * inv * gv.y + bb.y;
  ov.z = (x2 - mu) * inv * gv.z + bb.z;
  ov.w = (x3 - mu) * inv * gv.w + bb.w;
  *reinterpret_cast<float4*>(out + base) = ov;
}

extern "C" void kernel_launch(void* const* d_in, const int* in_sizes, int n_in,
                              void* d_out, int out_size, void* d_ws, size_t ws_size,
                              hipStream_t stream) {
  const float* hs   = (const float*)d_in[0];
  const float* mask = (const float*)d_in[1];
  const float* Wq   = (const float*)d_in[2];
  const float* bq   = (const float*)d_in[3];
  const float* Wk   = (const float*)d_in[4];
  const float* bk   = (const float*)d_in[5];
  const float* Wv   = (const float*)d_in[6];
  const float* bv   = (const float*)d_in[7];
  const float* Wd   = (const float*)d_in[8];
  const float* bd   = (const float*)d_in[9];
  const float* lng  = (const float*)d_in[10];
  const float* lnb  = (const float*)d_in[11];
  float* out = (float*)d_out;

  char* ws = (char*)d_ws;
  const size_t SZ_X = (size_t)B_ * S_ * H_ * 2;
  const size_t SZ_W = (size_t)H_ * H_ * 2;
  unsigned short* Xb  = (unsigned short*)(ws);
  unsigned short* Wqb = (unsigned short*)(ws + SZ_X);
  unsigned short* Wkb = (unsigned short*)(ws + SZ_X + SZ_W);
  unsigned short* Wvb = (unsigned short*)(ws + SZ_X + 2 * SZ_W);
  unsigned short* Wdb = (unsigned short*)(ws + SZ_X + 3 * SZ_W);
  unsigned short* Qb  = (unsigned short*)(ws + SZ_X + 4 * SZ_W);
  unsigned short* Kb  = (unsigned short*)(ws + 2 * SZ_X + 4 * SZ_W);
  unsigned short* Vb  = (unsigned short*)(ws + 3 * SZ_X + 4 * SZ_W);
  unsigned short* Cxb = (unsigned short*)(ws + 4 * SZ_X + 4 * SZ_W);
  float* Proj         = (float*)(ws + 5 * SZ_X + 4 * SZ_W);

  const int NX = B_ * S_ * H_;
  const int NW = H_ * H_;

  cvt_kernel<<<NX / 1024, 256, 0, stream>>>(hs, Xb, NX);
  dim3 gw(NW / 1024, 4);
  cvtw_kernel<<<gw, 256, 0, stream>>>(Wq, Wk, Wv, Wd, Wqb, Wkb, Wvb, Wdb, NW);

  dim3 gg(B_ * S_ / 128, H_ / 128);
  gemm_bt<true><<<gg, 256, 0, stream>>>(Xb, Wqb, bq, Qb, B_ * S_, H_, H_);
  gemm_bt<true><<<gg, 256, 0, stream>>>(Xb, Wkb, bk, Kb, B_ * S_, H_, H_);
  gemm_bt<true><<<gg, 256, 0, stream>>>(Xb, Wvb, bv, Vb, B_ * S_, H_, H_);

  attn_kernel<<<dim3((S_ / 128) * NH_ * B_), 256, 0, stream>>>(Qb, Kb, Vb, mask, Cxb);

  gemm_bt<false><<<gg, 256, 0, stream>>>(Cxb, Wdb, bd, Proj, B_ * S_, H_, H_);

  ln_kernel<<<B_ * S_, 256, 0, stream>>>(Proj, hs, lng, lnb, out);
}

// Round 9
// 272.303 us; speedup vs baseline: 1.1754x; 1.0753x over previous
//
#include <hip/hip_runtime.h>
#include <stdint.h>

#define B_ 4
#define S_ 2048
#define H_ 1024
#define NH_ 16
#define HD_ 64
#define KS_ 3072  // fused QKV row stride

typedef __bf16 bf16x8 __attribute__((ext_vector_type(8)));
typedef unsigned short u16x8 __attribute__((ext_vector_type(8)));
typedef float f32x4 __attribute__((ext_vector_type(4)));
typedef float f32x16 __attribute__((ext_vector_type(16)));

__device__ __forceinline__ unsigned short f2bf(float x) {
  union { float f; unsigned u; } c; c.f = x;
  unsigned r = (c.u + 0x7FFFu + ((c.u >> 16) & 1u)) >> 16;
  return (unsigned short)r;
}

__device__ __forceinline__ unsigned cvtpk(float lo, float hi) {
  unsigned r;
  asm("v_cvt_pk_bf16_f32 %0, %1, %2" : "=v"(r) : "v"(lo), "v"(hi));
  return r;
}

// xor-32 cross-half reduce via permlane32_swap (VALU only, no LDS pipe).
// swap(a,b): a' = {l<32: a[l], l>=32: b[l-32]}, b' = {l<32: a[l+32], l>=32: b[l]}
__device__ __forceinline__ float xmax32(float x) {
  float a = x, b = x;
  asm("v_permlane32_swap_b32 %0, %1" : "+v"(a), "+v"(b));
  return fmaxf(a, b);
}
__device__ __forceinline__ float xadd32(float x) {
  float a = x, b = x;
  asm("v_permlane32_swap_b32 %0, %1" : "+v"(a), "+v"(b));
  return a + b;
}

__device__ __forceinline__ void gload16(const unsigned short* g, unsigned short* lds) {
  __builtin_amdgcn_global_load_lds((const __attribute__((address_space(1))) void*)g,
                                   (__attribute__((address_space(3))) void*)lds, 16, 0, 0);
}

// ---------------- fp32 -> bf16 cast ----------------
__global__ __launch_bounds__(256) void cvt_kernel(const float* __restrict__ src,
                                                  unsigned short* __restrict__ dst, int n) {
  int i = (blockIdx.x * blockDim.x + threadIdx.x) * 4;
  if (i < n) {
    float4 v = *reinterpret_cast<const float4*>(src + i);
    ushort4 o;
    o.x = f2bf(v.x); o.y = f2bf(v.y); o.z = f2bf(v.z); o.w = f2bf(v.w);
    *reinterpret_cast<ushort4*>(dst + i) = o;
  }
}

// 4 weight matrices in one launch; q/k/v go concatenated into Wqkvb, plus bias concat.
__global__ __launch_bounds__(256) void cvtw_kernel(const float* __restrict__ w0,
                                                   const float* __restrict__ w1,
                                                   const float* __restrict__ w2,
                                                   const float* __restrict__ w3,
                                                   const float* __restrict__ bq,
                                                   const float* __restrict__ bk,
                                                   const float* __restrict__ bv,
                                                   unsigned short* __restrict__ wqkv,
                                                   unsigned short* __restrict__ wd,
                                                   float* __restrict__ bcat, int n) {
  const int which = blockIdx.y;
  const float* src = (which == 0) ? w0 : (which == 1) ? w1 : (which == 2) ? w2 : w3;
  unsigned short* dst = (which < 3) ? (wqkv + (size_t)which * n) : wd;
  int i = (blockIdx.x * blockDim.x + threadIdx.x) * 4;
  if (i < n) {
    float4 v = *reinterpret_cast<const float4*>(src + i);
    ushort4 o;
    o.x = f2bf(v.x); o.y = f2bf(v.y); o.z = f2bf(v.z); o.w = f2bf(v.w);
    *reinterpret_cast<ushort4*>(dst + i) = o;
  }
  if (blockIdx.x == 0 && which < 3) {
    const float* bs = (which == 0) ? bq : (which == 1) ? bk : bv;
    for (int j = threadIdx.x; j < H_; j += 256) bcat[which * H_ + j] = bs[j];
  }
}

// ---------------- bf16 GEMM, C[m,n] = sum_k A[m,k]*B[n,k] + bias[n] ----------------
template <bool BF16OUT>
__global__ __launch_bounds__(256) void gemm_bt(const unsigned short* __restrict__ A,
                                               const unsigned short* __restrict__ Bm,
                                               const float* __restrict__ bias,
                                               void* __restrict__ Cout,
                                               int M, int N, int K) {
  __shared__ unsigned short As[128 * 32];
  __shared__ unsigned short Bs[128 * 32];
  const int t = threadIdx.x;
  const int lane = t & 63;
  const int wv = t >> 6;
  const int wm = wv >> 1, wn = wv & 1;
  const int m0 = blockIdx.x * 128, n0 = blockIdx.y * 128;
  const int l15 = lane & 15, g8 = (lane >> 4) * 8;

  f32x4 acc[4][4];
#pragma unroll
  for (int i = 0; i < 4; ++i)
#pragma unroll
    for (int j = 0; j < 4; ++j) { f32x4 z = {0.f, 0.f, 0.f, 0.f}; acc[i][j] = z; }

  const int rowA = t >> 2;
  const int colA = (t & 3) * 8;
  const unsigned short* gA0 = A + (long)(m0 + rowA) * K + colA;
  const unsigned short* gA1 = A + (long)(m0 + 64 + rowA) * K + colA;
  const unsigned short* gB0 = Bm + (long)(n0 + rowA) * K + colA;
  const unsigned short* gB1 = Bm + (long)(n0 + 64 + rowA) * K + colA;
  unsigned short* ldsA0 = &As[wv * 512];
  unsigned short* ldsA1 = &As[2048 + wv * 512];
  unsigned short* ldsB0 = &Bs[wv * 512];
  unsigned short* ldsB1 = &Bs[2048 + wv * 512];

  for (int k0 = 0; k0 < K; k0 += 32) {
    __syncthreads();
    gload16(gA0 + k0, ldsA0);
    gload16(gA1 + k0, ldsA1);
    gload16(gB0 + k0, ldsB0);
    gload16(gB1 + k0, ldsB1);
    __syncthreads();

    bf16x8 af[4], bfr[4];
#pragma unroll
    for (int i = 0; i < 4; ++i)
      af[i] = *reinterpret_cast<const bf16x8*>(&As[(wm * 64 + i * 16 + l15) * 32 + g8]);
#pragma unroll
    for (int j = 0; j < 4; ++j)
      bfr[j] = *reinterpret_cast<const bf16x8*>(&Bs[(wn * 64 + j * 16 + l15) * 32 + g8]);
#pragma unroll
    for (int i = 0; i < 4; ++i)
#pragma unroll
      for (int j = 0; j < 4; ++j)
        acc[i][j] = __builtin_amdgcn_mfma_f32_16x16x32_bf16(af[i], bfr[j], acc[i][j], 0, 0, 0);
  }

  const int r0 = (lane >> 4) * 4;
#pragma unroll
  for (int i = 0; i < 4; ++i)
#pragma unroll
    for (int j = 0; j < 4; ++j) {
      int col = n0 + wn * 64 + j * 16 + l15;
      float bv = bias[col];
#pragma unroll
      for (int r = 0; r < 4; ++r) {
        int row = m0 + wm * 64 + i * 16 + r0 + r;
        float v = acc[i][j][r] + bv;
        if (BF16OUT)
          ((unsigned short*)Cout)[(long)row * N + col] = f2bf(v);
        else
          ((float*)Cout)[(long)row * N + col] = v;
      }
    }
}

// ---------------- flash attention: 32x32x16, dbuf, DMA K, XCD swizzle, T15 pipeline -----
// Flat grid 1024; bh = (id>>7)*8 + (id&7), qb = (id>>3)&15 -> all 16 q-blocks of
// one (b,h) on one XCD (K/V slice L2-resident). 4 waves; wave owns 32 q-rows.
// KV tile 64 (2 subtiles of 32), double-buffered. Q/K/V read from fused QKV
// buffer with row stride KS_=3072.
// Per iter: LOADK/LOADV(next) -> QK(sub0) -> QK(sub1) -> SMPV(0) -> SMPV(1)
// -> WRITEV(next) -> barrier. Sub1's MFMAs overlap sub0's softmax chain (T15).
// xor-32 reductions via v_permlane32_swap (VALU, no LDS pipe).
__global__ __launch_bounds__(256) void attn_kernel(const unsigned short* __restrict__ Q,
                                                   const unsigned short* __restrict__ Kg,
                                                   const unsigned short* __restrict__ Vg,
                                                   const float* __restrict__ mask,
                                                   unsigned short* __restrict__ ctx) {
  __shared__ __align__(16) unsigned short Kt[2][64 * 64];   // linear, DMA-written
  __shared__ __align__(16) unsigned short VtT[2][64 * 72];  // [d][kv swizzled], padded
  __shared__ __align__(16) float biasL[2][64];
  __shared__ __align__(16) float alBuf[4][32];
  __shared__ int mflag[2];
  __shared__ int anyMsh;

  const int t = threadIdx.x, lane = t & 63;
  const int wv = t >> 6;
  const int id = blockIdx.x;
  const int bh = ((id >> 7) << 3) | (id & 7);
  const int qb = (id >> 3) & 15;
  const int h = bh & 15, b = bh >> 4;
  const int q0w = qb * 128 + wv * 32;
  const int l31 = lane & 31, h2 = lane >> 5;
  const long headoff = (long)h * HD_;
  const float L2E = 1.44269504088896f;
  const float SC = 0.125f * L2E;

  // ---- block-level mask scan: fast path when mask row is all ones ----
  if (t == 0) anyMsh = 0;
  __syncthreads();
  {
    bool nz = false;
    for (int i = t; i < S_; i += 256) nz |= (mask[(long)b * S_ + i] != 1.0f);
    if (__any(nz) && lane == 0) atomicOr(&anyMsh, 1);
  }

  // Q B-fragments, prescaled
  bf16x8 qf[4];
  {
    const unsigned short* Qrow = Q + ((long)(b * S_ + q0w + l31)) * KS_ + headoff;
#pragma unroll
    for (int c = 0; c < 4; ++c) {
      bf16x8 raw = *reinterpret_cast<const bf16x8*>(Qrow + 16 * c + 8 * h2);
#pragma unroll
      for (int j = 0; j < 8; ++j) qf[c][j] = (__bf16)((float)raw[j] * SC);
    }
  }
  __syncthreads();
  const bool anyM = (anyMsh != 0);

  f32x16 o[2];
#pragma unroll
  for (int dt = 0; dt < 2; ++dt)
#pragma unroll
    for (int r = 0; r < 16; ++r) o[dt][r] = 0.f;
  float mrow = -1.0e30f, lsum = 0.f;

  // K read offsets (swizzled, loop-invariant)
  int koff[4];
#pragma unroll
  for (int c = 0; c < 4; ++c) koff[c] = 8 * ((2 * c + h2) ^ (l31 & 7));

  // V read offsets (swizzled, loop-invariant)
  const int rowd0 = l31, rowd1 = 32 + l31;
  const int grp0 = (rowd0 >> 3) & 7, grp1 = (rowd1 >> 3) & 7;
  int voff0[4], voff1[4];
#pragma unroll
  for (int kc = 0; kc < 4; ++kc) {
    voff0[kc] = rowd0 * 72 + 8 * ((2 * kc + h2) ^ grp0);
    voff1[kc] = rowd1 * 72 + 8 * ((2 * kc + h2) ^ grp1);
  }

  const long gbase = (long)(b * S_) * KS_ + headoff;

  // K DMA source (pre-swizzled): lane supplies row lane>>3, col-group (lane&7)^(lane>>3)
  const unsigned short* kg0 =
      Kg + gbase + (long)(16 * wv + (lane >> 3)) * KS_ + 8 * ((lane & 7) ^ (lane >> 3));
  const unsigned short* kg1 = kg0 + 8 * KS_;

  // V staging (regs): rows vrow, vrow+1, d-block dc
  const int vrow = (t >> 3) * 2, dc = t & 7;
  u16x8 vr0, vr1;

  auto LOADK = [&](int buf, int kv0) {
    gload16(kg0 + (long)kv0 * KS_, &Kt[buf][(16 * wv) * 64]);
    gload16(kg1 + (long)kv0 * KS_, &Kt[buf][(16 * wv + 8) * 64]);
  };
  auto LOADV = [&](int kv0) {
    vr0 = *reinterpret_cast<const u16x8*>(Vg + gbase + (long)(kv0 + vrow) * KS_ + dc * 8);
    vr1 = *reinterpret_cast<const u16x8*>(Vg + gbase + (long)(kv0 + vrow + 1) * KS_ + dc * 8);
  };
  auto WRITEV = [&](int buf, int kv0) {
    const int pos = (vrow & 7) | (((vrow >> 3) ^ dc) << 3);
#pragma unroll
    for (int j = 0; j < 8; ++j) {
      ushort2 pr; pr.x = vr0[j]; pr.y = vr1[j];
      *reinterpret_cast<ushort2*>(&VtT[buf][(dc * 8 + j) * 72 + pos]) = pr;
    }
    if (anyM && t < 64) {
      float mv = mask[(long)b * S_ + kv0 + t];
      biasL[buf][t] = (1.f - mv) * (-10000.f * L2E);
      unsigned long long bal = __ballot(mv != 1.0f);
      if (t == 0) mflag[buf] = (bal != 0ull);
    }
  };

  // softmax + PV for one 32-kv subtile
  auto SMPV = [&](f32x16& sv, int kvt, int cur) {
    float m0 = fmaxf(fmaxf(sv[0], sv[1]), sv[2]);
    float m1 = fmaxf(fmaxf(sv[3], sv[4]), sv[5]);
    float m2 = fmaxf(fmaxf(sv[6], sv[7]), sv[8]);
    float m3 = fmaxf(fmaxf(sv[9], sv[10]), sv[11]);
    float m4 = fmaxf(fmaxf(sv[12], sv[13]), sv[14]);
    float t0 = fmaxf(fmaxf(m0, m1), m2);
    float t1 = fmaxf(fmaxf(m3, m4), sv[15]);
    float tm = xmax32(fmaxf(t0, t1));
    if (!__all(tm <= mrow + 8.0f)) {  // defer-max THR=8 (log2 domain)
      float mn = fmaxf(mrow, tm);
      float al = exp2f(mrow - mn);
      mrow = mn;
      lsum *= al;
      if (lane < 32) alBuf[wv][lane] = al;
      __builtin_amdgcn_wave_barrier();
#pragma unroll
      for (int m = 0; m < 4; ++m) {
        f32x4 av = *reinterpret_cast<const f32x4*>(&alBuf[wv][8 * m + 4 * h2]);
#pragma unroll
        for (int i = 0; i < 4; ++i) {
          o[0][4 * m + i] *= av[i];
          o[1][4 * m + i] *= av[i];
        }
      }
    }
#pragma unroll
    for (int r = 0; r < 16; ++r) sv[r] = exp2f(sv[r] - mrow);
    {
      float s0 = sv[0] + sv[1], s1 = sv[2] + sv[3], s2 = sv[4] + sv[5], s3 = sv[6] + sv[7];
      float s4 = sv[8] + sv[9], s5 = sv[10] + sv[11], s6 = sv[12] + sv[13], s7 = sv[14] + sv[15];
      float u0 = s0 + s1, u1 = s2 + s3, u2 = s4 + s5, u3 = s6 + s7;
      lsum += xadd32((u0 + u1) + (u2 + u3));
    }
#pragma unroll
    for (int c2 = 0; c2 < 2; ++c2) {
      const int kc = 2 * kvt + c2;
      unsigned p0 = cvtpk(sv[8 * c2 + 0], sv[8 * c2 + 1]);
      unsigned p1 = cvtpk(sv[8 * c2 + 2], sv[8 * c2 + 3]);
      unsigned p2 = cvtpk(sv[8 * c2 + 4], sv[8 * c2 + 5]);
      unsigned p3 = cvtpk(sv[8 * c2 + 6], sv[8 * c2 + 7]);
      asm("v_permlane32_swap_b32 %0, %1" : "+v"(p0), "+v"(p2));
      asm("v_permlane32_swap_b32 %0, %1" : "+v"(p1), "+v"(p3));
      union { unsigned w[4]; bf16x8 v; } fa;
      fa.w[0] = p0; fa.w[1] = p1; fa.w[2] = p2; fa.w[3] = p3;

      bf16x8 vb0 = *reinterpret_cast<const bf16x8*>(&VtT[cur][voff0[kc]]);
      bf16x8 vb1 = *reinterpret_cast<const bf16x8*>(&VtT[cur][voff1[kc]]);
      __builtin_amdgcn_s_setprio(1);
      o[0] = __builtin_amdgcn_mfma_f32_32x32x16_bf16(fa.v, vb0, o[0], 0, 0, 0);
      o[1] = __builtin_amdgcn_mfma_f32_32x32x16_bf16(fa.v, vb1, o[1], 0, 0, 0);
      __builtin_amdgcn_s_setprio(0);
    }
  };

  const int NT = S_ / 64;
  LOADK(0, 0);
  LOADV(0);
  WRITEV(0, 0);
  __syncthreads();  // drains DMA (vmcnt) + V writes

  for (int it = 0; it < NT; ++it) {
    const int cur = it & 1;
    const bool more = (it + 1 < NT);
    if (more) {
      LOADK(cur ^ 1, (it + 1) * 64);
      LOADV((it + 1) * 64);
    }

    // T15: both QK subtiles first (independent MFMA work overlaps SMPV(0) chain)
    f32x16 sv0, sv1;
#pragma unroll
    for (int r = 0; r < 16; ++r) { sv0[r] = 0.f; sv1[r] = 0.f; }
    const int rb0 = l31 * 64, rb1 = (32 + l31) * 64;
    __builtin_amdgcn_s_setprio(1);
#pragma unroll
    for (int c = 0; c < 4; ++c) {
      bf16x8 af = *reinterpret_cast<const bf16x8*>(&Kt[cur][rb0 + koff[c]]);
      sv0 = __builtin_amdgcn_mfma_f32_32x32x16_bf16(af, qf[c], sv0, 0, 0, 0);
    }
#pragma unroll
    for (int c = 0; c < 4; ++c) {
      bf16x8 af = *reinterpret_cast<const bf16x8*>(&Kt[cur][rb1 + koff[c]]);
      sv1 = __builtin_amdgcn_mfma_f32_32x32x16_bf16(af, qf[c], sv1, 0, 0, 0);
    }
    __builtin_amdgcn_s_setprio(0);

    if (anyM && mflag[cur]) {
#pragma unroll
      for (int m = 0; m < 4; ++m) {
        f32x4 b0 = *reinterpret_cast<const f32x4*>(&biasL[cur][8 * m + 4 * h2]);
        f32x4 b1 = *reinterpret_cast<const f32x4*>(&biasL[cur][32 + 8 * m + 4 * h2]);
#pragma unroll
        for (int i = 0; i < 4; ++i) { sv0[4 * m + i] += b0[i]; sv1[4 * m + i] += b1[i]; }
      }
    }

    SMPV(sv0, 0, cur);
    SMPV(sv1, 1, cur);

    if (more) {
      WRITEV(cur ^ 1, (it + 1) * 64);
      __syncthreads();
    }
  }

  // ---- epilogue ----
  if (lane < 32) alBuf[wv][lane] = 1.0f / lsum;
  __builtin_amdgcn_wave_barrier();
  unsigned short* ctxbase = ctx + ((long)(b * S_ + q0w + 4 * h2)) * H_ + headoff + l31;
#pragma unroll
  for (int m = 0; m < 4; ++m) {
    f32x4 iv = *reinterpret_cast<const f32x4*>(&alBuf[wv][8 * m + 4 * h2]);
#pragma unroll
    for (int i = 0; i < 4; ++i) {
#pragma unroll
      for (int dt = 0; dt < 2; ++dt)
        ctxbase[(long)(8 * m + i) * H_ + dt * 32] = f2bf(o[dt][4 * m + i] * iv[i]);
    }
  }
}

// ---------------- residual + LayerNorm ----------------
__global__ __launch_bounds__(256) void ln_kernel(const float* __restrict__ proj,
                                                 const float* __restrict__ hs,
                                                 const float* __restrict__ gam,
                                                 const float* __restrict__ bet,
                                                 float* __restrict__ out) {
  const int row = blockIdx.x;
  const int t = threadIdx.x;
  const long base = (long)row * H_ + t * 4;
  float4 a = *reinterpret_cast<const float4*>(proj + base);
  float4 hv = *reinterpret_cast<const float4*>(hs + base);
  float x0 = a.x + hv.x, x1 = a.y + hv.y, x2 = a.z + hv.z, x3 = a.w + hv.w;
  float s1 = x0 + x1 + x2 + x3;
  float s2 = x0 * x0 + x1 * x1 + x2 * x2 + x3 * x3;
#pragma unroll
  for (int off = 1; off < 64; off <<= 1) {
    s1 += __shfl_xor(s1, off);
    s2 += __shfl_xor(s2, off);
  }
  __shared__ float a1[4], a2[4];
  if ((t & 63) == 0) { a1[t >> 6] = s1; a2[t >> 6] = s2; }
  __syncthreads();
  float ts1 = a1[0] + a1[1] + a1[2] + a1[3];
  float ts2 = a2[0] + a2[1] + a2[2] + a2[3];
  float mu = ts1 * (1.0f / H_);
  float var = ts2 * (1.0f / H_) - mu * mu;
  float inv = rsqrtf(var + 1e-12f);
  float4 gv = *reinterpret_cast<const float4*>(gam + t * 4);
  float4 bb = *reinterpret_cast<const float4*>(bet + t * 4);
  float4 ov;
  ov.x = (x0 - mu) * inv * gv.x + bb.x;
  ov.y = (x1 - mu) * inv * gv.y + bb.y;
  ov.z = (x2 - mu) * inv * gv.z + bb.z;
  ov.w = (x3 - mu) * inv * gv.w + bb.w;
  *reinterpret_cast<float4*>(out + base) = ov;
}

extern "C" void kernel_launch(void* const* d_in, const int* in_sizes, int n_in,
                              void* d_out, int out_size, void* d_ws, size_t ws_size,
                              hipStream_t stream) {
  const float* hs   = (const float*)d_in[0];
  const float* mask = (const float*)d_in[1];
  const float* Wq   = (const float*)d_in[2];
  const float* bq   = (const float*)d_in[3];
  const float* Wk   = (const float*)d_in[4];
  const float* bk   = (const float*)d_in[5];
  const float* Wv   = (const float*)d_in[6];
  const float* bv   = (const float*)d_in[7];
  const float* Wd   = (const float*)d_in[8];
  const float* bd   = (const float*)d_in[9];
  const float* lng  = (const float*)d_in[10];
  const float* lnb  = (const float*)d_in[11];
  float* out = (float*)d_out;

  char* ws = (char*)d_ws;
  const size_t SZ_X = (size_t)B_ * S_ * H_ * 2;   // 16.8 MB
  const size_t SZ_W = (size_t)H_ * H_ * 2;        // 2.1 MB
  unsigned short* Xb    = (unsigned short*)(ws);
  unsigned short* Wqkvb = (unsigned short*)(ws + SZ_X);
  unsigned short* Wdb   = (unsigned short*)(ws + SZ_X + 3 * SZ_W);
  float*          bcat  = (float*)(ws + SZ_X + 4 * SZ_W);
  unsigned short* QKVb  = (unsigned short*)(ws + SZ_X + 4 * SZ_W + 16384);
  unsigned short* Cxb   = (unsigned short*)(ws + 4 * SZ_X + 4 * SZ_W + 16384);
  float*          Proj  = (float*)(ws + 5 * SZ_X + 4 * SZ_W + 16384);

  const int NX = B_ * S_ * H_;
  const int NW = H_ * H_;

  cvt_kernel<<<NX / 1024, 256, 0, stream>>>(hs, Xb, NX);
  dim3 gw(NW / 1024, 4);
  cvtw_kernel<<<gw, 256, 0, stream>>>(Wq, Wk, Wv, Wd, bq, bk, bv, Wqkvb, Wdb, bcat, NW);

  // fused QKV projection: M=8192, N=3072, K=1024
  dim3 gq(B_ * S_ / 128, KS_ / 128);  // (64, 24)
  gemm_bt<true><<<gq, 256, 0, stream>>>(Xb, Wqkvb, bcat, QKVb, B_ * S_, KS_, H_);

  attn_kernel<<<dim3((S_ / 128) * NH_ * B_), 256, 0, stream>>>(
      QKVb, QKVb + 1024, QKVb + 2048, mask, Cxb);

  dim3 gg(B_ * S_ / 128, H_ / 128);
  gemm_bt<false><<<gg, 256, 0, stream>>>(Cxb, Wdb, bd, Proj, B_ * S_, H_, H_);

  ln_kernel<<<B_ * S_, 256, 0, stream>>>(Proj, hs, lng, lnb, out);
}